// Round 14
// baseline (284.219 us; speedup 1.0000x reference)
//
#include <hip/hip_runtime.h>
#include <math.h>

#define NN 50000
#define NE 800000
#define NT (NN + NE)     // 850000 edges incl self-loops; NE,NT divisible by 4
#define SCAN_BLOCKS 196  // 196*256 = 50176 >= NN

__device__ __forceinline__ float lrelu(float a) { return a > 0.f ? a : 0.2f * a; }

__device__ __forceinline__ float sel4(float4 v, int h) {
  float r = v.x;
  r = (h == 1) ? v.y : r;
  r = (h == 2) ? v.z : r;
  r = (h == 3) ? v.w : r;
  return r;
}

// bf16 helpers: packed pair = lo | hi<<16, RNE rounding
__device__ __forceinline__ unsigned int f2bf(float f) {
  unsigned int u = __float_as_uint(f);
  return (u + 0x7FFFu + ((u >> 16) & 1u)) >> 16;
}
__device__ __forceinline__ unsigned int packbf(float lo, float hi) {
  return f2bf(lo) | (f2bf(hi) << 16);
}
__device__ __forceinline__ float bflo(unsigned int v) { return __uint_as_float(v << 16); }
__device__ __forceinline__ float bfhi(unsigned int v) { return __uint_as_float(v & 0xFFFF0000u); }

// per-wave int64 detection: probe odd 32-bit words of the wave's first 64 src
// entries. int64 => high words all zero. Wave edge-chunks are 256-aligned and
// NE % 256 == 0, so a wave is entirely in the edge region or entirely self-loop.
__device__ __forceinline__ int wave_is64(const void* eb, int wbase, int lane) {
  unsigned int probe = ((const unsigned int*)eb)[2 * (size_t)(wbase + lane) + 1];
  return (__ballot(probe != 0u) == 0ULL) ? 1 : 0;
}

// ---------------- CSR build pass 1: within-segment ranks (4 edges/thread) ----------
__global__ __launch_bounds__(256) void k_pass1(const void* __restrict__ eb,
                                               int* __restrict__ cnt,
                                               unsigned int* __restrict__ pw) {
  int e0 = (blockIdx.x * 256 + threadIdx.x) * 4;
  if (e0 >= NT) return;
  int lane = threadIdx.x & 63;
  int d0, d1, d2, d3;
  if (e0 < NE) {
    int wbase = (blockIdx.x * 256 + (threadIdx.x & ~63)) * 4;
    int is64 = wave_is64(eb, wbase, lane);
    if (is64) {
      const uint4* p = (const uint4*)((const unsigned int*)eb + 2 * ((size_t)NE + e0));
      uint4 a = p[0], b = p[1];
      d0 = (int)a.x; d1 = (int)a.z; d2 = (int)b.x; d3 = (int)b.z;
    } else {
      int4 v = *(const int4*)((const int*)eb + (size_t)NE + e0);
      d0 = v.x; d1 = v.y; d2 = v.z; d3 = v.w;
    }
  } else {
    d0 = e0 - NE; d1 = d0 + 1; d2 = d0 + 2; d3 = d0 + 3;
  }
  unsigned int p0 = (unsigned int)atomicAdd(&cnt[d0], 1);
  unsigned int p1 = (unsigned int)atomicAdd(&cnt[d1], 1);
  unsigned int p2 = (unsigned int)atomicAdd(&cnt[d2], 1);
  unsigned int p3 = (unsigned int)atomicAdd(&cnt[d3], 1);
  *(uint4*)&pw[e0] = make_uint4(p0, p1, p2, p3);
}

// block sums of cnt
__global__ __launch_bounds__(256) void k_bsum(const int* __restrict__ cnt,
                                              int* __restrict__ bsum) {
  int i = blockIdx.x * 256 + threadIdx.x;
  int v = (i < NN) ? cnt[i] : 0;
#pragma unroll
  for (int off = 1; off < 64; off <<= 1) v += __shfl_xor(v, off, 64);
  __shared__ int ws[4];
  int lane = threadIdx.x & 63, wid = threadIdx.x >> 6;
  if (lane == 0) ws[wid] = v;
  __syncthreads();
  if (threadIdx.x == 0) bsum[blockIdx.x] = ws[0] + ws[1] + ws[2] + ws[3];
}

// rowp: each block redundantly scans bsum (196 entries) for its base offset,
// then does the block-local exclusive scan of its cnt chunk.
__global__ __launch_bounds__(256) void k_rowp(const int* __restrict__ cnt,
                                              const int* __restrict__ bsum,
                                              int* __restrict__ rowp) {
  __shared__ int pref[256];
  __shared__ int wsum1[4], woff1[4];
  int t = threadIdx.x;
  int lane = t & 63, wid = t >> 6;
  // phase 1: exclusive scan of bsum -> pref
  {
    int v = (t < SCAN_BLOCKS) ? bsum[t] : 0;
    int incl = v;
#pragma unroll
    for (int off = 1; off < 64; off <<= 1) {
      int u = __shfl_up(incl, off, 64);
      if (lane >= off) incl += u;
    }
    if (lane == 63) wsum1[wid] = incl;
    __syncthreads();
    if (t == 0) {
      woff1[0] = 0;
      woff1[1] = wsum1[0];
      woff1[2] = wsum1[0] + wsum1[1];
      woff1[3] = wsum1[0] + wsum1[1] + wsum1[2];
    }
    __syncthreads();
    pref[t] = woff1[wid] + incl - v;
    __syncthreads();
  }
  int boffb = pref[blockIdx.x];
  // phase 2: local scan of this block's cnt chunk
  __shared__ int wsum2[4], woff2[4];
  int i = blockIdx.x * 256 + t;
  int v = (i < NN) ? cnt[i] : 0;
  int incl = v;
#pragma unroll
  for (int off = 1; off < 64; off <<= 1) {
    int u = __shfl_up(incl, off, 64);
    if (lane >= off) incl += u;
  }
  if (lane == 63) wsum2[wid] = incl;
  __syncthreads();
  if (t == 0) {
    woff2[0] = 0;
    woff2[1] = wsum2[0];
    woff2[2] = wsum2[0] + wsum2[1];
    woff2[3] = wsum2[0] + wsum2[1] + wsum2[2];
  }
  __syncthreads();
  if (i < NN) rowp[i] = boffb + woff2[wid] + incl - v;
  if (blockIdx.x == 0 && t == 0) rowp[NN] = NT;
}

// ---------------- CSR build pass 2: deterministic scatter, no atomics ---------------
__global__ __launch_bounds__(256) void k_pass2(const void* __restrict__ eb,
                                               const int* __restrict__ rowp,
                                               const unsigned int* __restrict__ pw,
                                               int* __restrict__ csr) {
  int e0 = (blockIdx.x * 256 + threadIdx.x) * 4;
  if (e0 >= NT) return;
  int lane = threadIdx.x & 63;
  int s0, s1, s2, s3, d0, d1, d2, d3;
  if (e0 < NE) {
    int wbase = (blockIdx.x * 256 + (threadIdx.x & ~63)) * 4;
    int is64 = wave_is64(eb, wbase, lane);
    if (is64) {
      const uint4* ps = (const uint4*)((const unsigned int*)eb + 2 * (size_t)e0);
      uint4 a = ps[0], b = ps[1];
      s0 = (int)a.x; s1 = (int)a.z; s2 = (int)b.x; s3 = (int)b.z;
      const uint4* pd = (const uint4*)((const unsigned int*)eb + 2 * ((size_t)NE + e0));
      uint4 c = pd[0], d = pd[1];
      d0 = (int)c.x; d1 = (int)c.z; d2 = (int)d.x; d3 = (int)d.z;
    } else {
      int4 vs = *(const int4*)((const int*)eb + (size_t)e0);
      s0 = vs.x; s1 = vs.y; s2 = vs.z; s3 = vs.w;
      int4 vd = *(const int4*)((const int*)eb + (size_t)NE + e0);
      d0 = vd.x; d1 = vd.y; d2 = vd.z; d3 = vd.w;
    }
  } else {
    s0 = d0 = e0 - NE;
    s1 = d1 = d0 + 1;
    s2 = d2 = d0 + 2;
    s3 = d3 = d0 + 3;
  }
  uint4 pv = *(const uint4*)&pw[e0];
  csr[rowp[d0] + (int)pv.x] = s0;
  csr[rowp[d1] + (int)pv.y] = s1;
  csr[rowp[d2] + (int)pv.z] = s2;
  csr[rowp[d3] + (int)pv.w] = s3;
}

// ---------------- GEMM1 + fused attn1: 32x128 tile, 8x2 blocking --------------------
__global__ __launch_bounds__(256) void k_gemm1(const float* __restrict__ X,
                                               const float* __restrict__ W,
                                               const float* __restrict__ a_src,
                                               const float* __restrict__ a_dst,
                                               unsigned int* __restrict__ Hb,
                                               float* __restrict__ AS,
                                               float* __restrict__ AD) {
  __shared__ float xt[32 * 36];   // xt[k][row]
  __shared__ float wt[32 * 132];  // wt[k][col]
  int tid = threadIdx.x;
  int tr = tid >> 6, tc = tid & 63;
  int r0 = blockIdx.x * 32;
  float acc[8][2];
#pragma unroll
  for (int i = 0; i < 8; ++i) {
    acc[i][0] = 0.f;
    acc[i][1] = 0.f;
  }

  for (int kb = 0; kb < 4; ++kb) {
    __syncthreads();
    {
      int row = tid >> 3, k4 = tid & 7;
      int gr = r0 + row;
      float4 v = make_float4(0.f, 0.f, 0.f, 0.f);
      if (gr < NN) v = ((const float4*)X)[(size_t)gr * 32 + kb * 8 + k4];
      xt[(k4 * 4 + 0) * 36 + row] = v.x;
      xt[(k4 * 4 + 1) * 36 + row] = v.y;
      xt[(k4 * 4 + 2) * 36 + row] = v.z;
      xt[(k4 * 4 + 3) * 36 + row] = v.w;
    }
#pragma unroll
    for (int i = tid; i < 1024; i += 256) {
      int kr = i >> 5, c4 = i & 31;
      *(float4*)&wt[kr * 132 + c4 * 4] = ((const float4*)W)[(size_t)(kb * 32 + kr) * 32 + c4];
    }
    __syncthreads();
#pragma unroll 4
    for (int k = 0; k < 32; ++k) {
      float4 xa = *(const float4*)&xt[k * 36 + tr * 8];
      float4 xb = *(const float4*)&xt[k * 36 + tr * 8 + 4];
      float2 wv = *(const float2*)&wt[k * 132 + tc * 2];
      float xr[8] = {xa.x, xa.y, xa.z, xa.w, xb.x, xb.y, xb.z, xb.w};
#pragma unroll
      for (int i = 0; i < 8; ++i) {
        acc[i][0] += xr[i] * wv.x;
        acc[i][1] += xr[i] * wv.y;
      }
    }
  }
  int head = tc >> 4;
  float2 sv = *(const float2*)&a_src[tc * 2];
  float2 dv = *(const float2*)&a_dst[tc * 2];
#pragma unroll
  for (int i = 0; i < 8; ++i) {
    int gr = r0 + tr * 8 + i;
    float ps = acc[i][0] * sv.x + acc[i][1] * sv.y;
    float pd = acc[i][0] * dv.x + acc[i][1] * dv.y;
#pragma unroll
    for (int off = 1; off < 16; off <<= 1) {
      ps += __shfl_xor(ps, off, 64);
      pd += __shfl_xor(pd, off, 64);
    }
    if (gr < NN) {
      Hb[(size_t)gr * 64 + tc] = packbf(acc[i][0], acc[i][1]);
      if ((tc & 15) == 0) {
        AS[gr * 4 + head] = ps;
        AD[gr * 4 + head] = pd;
      }
    }
  }
}

// ---------------- layer-1 node + fused GEMM2 + attn2 (wave per dst) -----------------
// HM row computed in-register (fused softmax aggregation), then matvec vs W2 in-wave.
// Outputs: Hb2 (bf16 [NN][32], 4 uint4/row), AS2/AD2 (fp32 per node)
__global__ __launch_bounds__(256) void k_l1g2(const int* __restrict__ rowp,
                                              const int* __restrict__ csr,
                                              const uint4* __restrict__ Hb,
                                              const float* __restrict__ AS,
                                              const float* __restrict__ AD,
                                              const float* __restrict__ b1,
                                              const float* __restrict__ W2,
                                              const float* __restrict__ as2,
                                              const float* __restrict__ ad2,
                                              uint4* __restrict__ Hb2,
                                              float* __restrict__ AS2,
                                              float* __restrict__ AD2) {
  __shared__ float wsm[128 * 32];  // W2, 16 KB
  int tid = threadIdx.x;
  for (int i = tid; i < 1024; i += 256) ((float4*)wsm)[i] = ((const float4*)W2)[i];
  __syncthreads();

  int lane = tid & 63, wid = tid >> 6;
  int n = blockIdx.x * 4 + wid;
  if (n >= NN) return;
  int beg = rowp[n], end = rowp[n + 1];
  float4 ad4 = *(const float4*)&AD[n * 4];

  int sl = lane & 15;  // col slot: 8 cols at sl*8
  int g = lane >> 4;   // subgroup 0..3
  int hd = sl >> 2;
  float adh = sel4(ad4, hd);

  float a0 = 0.f, a1 = 0.f, a2 = 0.f, a3 = 0.f, a4 = 0.f, a5 = 0.f, a6 = 0.f, a7 = 0.f;
  float esum = 0.f;
  int i = beg + g;
  for (; i + 4 < end; i += 8) {
    int sA = csr[i];
    int sB = csr[i + 4];
    float lA = AS[sA * 4 + hd];
    float lB = AS[sB * 4 + hd];
    uint4 hA = Hb[(size_t)sA * 16 + sl];
    uint4 hB = Hb[(size_t)sB * 16 + sl];
    float wA = __expf(lrelu(lA + adh));
    float wB = __expf(lrelu(lB + adh));
    esum += wA + wB;
    a0 += wA * bflo(hA.x) + wB * bflo(hB.x);
    a1 += wA * bfhi(hA.x) + wB * bfhi(hB.x);
    a2 += wA * bflo(hA.y) + wB * bflo(hB.y);
    a3 += wA * bfhi(hA.y) + wB * bfhi(hB.y);
    a4 += wA * bflo(hA.z) + wB * bflo(hB.z);
    a5 += wA * bfhi(hA.z) + wB * bfhi(hB.z);
    a6 += wA * bflo(hA.w) + wB * bflo(hB.w);
    a7 += wA * bfhi(hA.w) + wB * bfhi(hB.w);
  }
  if (i < end) {
    int s = csr[i];
    float l = AS[s * 4 + hd];
    uint4 hv = Hb[(size_t)s * 16 + sl];
    float w0 = __expf(lrelu(l + adh));
    esum += w0;
    a0 += w0 * bflo(hv.x);
    a1 += w0 * bfhi(hv.x);
    a2 += w0 * bflo(hv.y);
    a3 += w0 * bfhi(hv.y);
    a4 += w0 * bflo(hv.z);
    a5 += w0 * bfhi(hv.z);
    a6 += w0 * bflo(hv.w);
    a7 += w0 * bfhi(hv.w);
  }
#pragma unroll
  for (int off = 16; off < 64; off <<= 1) {
    esum += __shfl_xor(esum, off, 64);
    a0 += __shfl_xor(a0, off, 64);
    a1 += __shfl_xor(a1, off, 64);
    a2 += __shfl_xor(a2, off, 64);
    a3 += __shfl_xor(a3, off, 64);
    a4 += __shfl_xor(a4, off, 64);
    a5 += __shfl_xor(a5, off, 64);
    a6 += __shfl_xor(a6, off, 64);
    a7 += __shfl_xor(a7, off, 64);
  }
  // all lanes: bias + relu -> HM cols sl*8..sl*8+7 (fp32, no intermediate rounding)
  float r = 1.f / esum;
  int c = sl * 8;
  float4 bva = *(const float4*)&b1[c];
  float4 bvb = *(const float4*)&b1[c + 4];
  float v[8];
  v[0] = fmaxf(a0 * r + bva.x, 0.f);
  v[1] = fmaxf(a1 * r + bva.y, 0.f);
  v[2] = fmaxf(a2 * r + bva.z, 0.f);
  v[3] = fmaxf(a3 * r + bva.w, 0.f);
  v[4] = fmaxf(a4 * r + bvb.x, 0.f);
  v[5] = fmaxf(a5 * r + bvb.y, 0.f);
  v[6] = fmaxf(a6 * r + bvb.z, 0.f);
  v[7] = fmaxf(a7 * r + bvb.w, 0.f);

  // fused GEMM2: lane (g,sl) -> outputs jb..jb+7 partial over k = sl*8..sl*8+7
  int jb = g * 8;
  float p[8] = {0.f, 0.f, 0.f, 0.f, 0.f, 0.f, 0.f, 0.f};
#pragma unroll
  for (int t = 0; t < 8; ++t) {
    int k = sl * 8 + t;
    float vt = v[t];
    float4 wA = *(const float4*)&wsm[k * 32 + jb];
    float4 wB = *(const float4*)&wsm[k * 32 + jb + 4];
    p[0] += vt * wA.x;
    p[1] += vt * wA.y;
    p[2] += vt * wA.z;
    p[3] += vt * wA.w;
    p[4] += vt * wB.x;
    p[5] += vt * wB.y;
    p[6] += vt * wB.z;
    p[7] += vt * wB.w;
  }
  // reduce over the 16 sl-classes
#pragma unroll
  for (int off = 1; off < 16; off <<= 1) {
    p[0] += __shfl_xor(p[0], off, 64);
    p[1] += __shfl_xor(p[1], off, 64);
    p[2] += __shfl_xor(p[2], off, 64);
    p[3] += __shfl_xor(p[3], off, 64);
    p[4] += __shfl_xor(p[4], off, 64);
    p[5] += __shfl_xor(p[5], off, 64);
    p[6] += __shfl_xor(p[6], off, 64);
    p[7] += __shfl_xor(p[7], off, 64);
  }
  // attn2 dots: subgroup partial over jb..jb+7, then cross-subgroup reduce
  float4 s2a = *(const float4*)&as2[jb];
  float4 s2b = *(const float4*)&as2[jb + 4];
  float4 d2a = *(const float4*)&ad2[jb];
  float4 d2b = *(const float4*)&ad2[jb + 4];
  float ps = p[0] * s2a.x + p[1] * s2a.y + p[2] * s2a.z + p[3] * s2a.w +
             p[4] * s2b.x + p[5] * s2b.y + p[6] * s2b.z + p[7] * s2b.w;
  float pd = p[0] * d2a.x + p[1] * d2a.y + p[2] * d2a.z + p[3] * d2a.w +
             p[4] * d2b.x + p[5] * d2b.y + p[6] * d2b.z + p[7] * d2b.w;
  ps += __shfl_xor(ps, 16, 64);
  ps += __shfl_xor(ps, 32, 64);
  pd += __shfl_xor(pd, 16, 64);
  pd += __shfl_xor(pd, 32, 64);

  if (sl == 0) {
    Hb2[(size_t)n * 4 + g] = make_uint4(packbf(p[0], p[1]), packbf(p[2], p[3]),
                                        packbf(p[4], p[5]), packbf(p[6], p[7]));
  }
  if (lane == 0) {
    AS2[n] = ps;
    AD2[n] = pd;
  }
}

// ---------------- layer-2: single-pass fused softmax + aggregation + sigmoid --------
__global__ __launch_bounds__(256) void k_l2node(const int* __restrict__ rowp,
                                                const int* __restrict__ csr,
                                                const uint2* __restrict__ Hb2,
                                                const float* __restrict__ AS,
                                                const float* __restrict__ AD,
                                                const float* __restrict__ b2,
                                                float* __restrict__ out) {
  int lane = threadIdx.x & 63, wid = threadIdx.x >> 6;
  int n = blockIdx.x * 4 + wid;
  if (n >= NN) return;
  int beg = rowp[n], end = rowp[n + 1];
  float adn = AD[n];

  int sl = lane & 7;  // 4 cols at sl*4 (bf16 row = 8 uint2 = 64B)
  int g = lane >> 3;  // subgroup 0..7, one edge each
  float a0 = 0.f, a1 = 0.f, a2 = 0.f, a3 = 0.f;
  float esum = 0.f;
  int i = beg + g;
  for (; i + 8 < end; i += 16) {
    int sA = csr[i];
    int sB = csr[i + 8];
    float lA = AS[sA];
    float lB = AS[sB];
    uint2 hA = Hb2[(size_t)sA * 8 + sl];
    uint2 hB = Hb2[(size_t)sB * 8 + sl];
    float wA = __expf(lrelu(lA + adn));
    float wB = __expf(lrelu(lB + adn));
    esum += wA + wB;
    a0 += wA * bflo(hA.x) + wB * bflo(hB.x);
    a1 += wA * bfhi(hA.x) + wB * bfhi(hB.x);
    a2 += wA * bflo(hA.y) + wB * bflo(hB.y);
    a3 += wA * bfhi(hA.y) + wB * bfhi(hB.y);
  }
  if (i < end) {
    int s = csr[i];
    float l = AS[s];
    uint2 hv = Hb2[(size_t)s * 8 + sl];
    float w0 = __expf(lrelu(l + adn));
    esum += w0;
    a0 += w0 * bflo(hv.x);
    a1 += w0 * bfhi(hv.x);
    a2 += w0 * bflo(hv.y);
    a3 += w0 * bfhi(hv.y);
  }
#pragma unroll
  for (int off = 8; off < 64; off <<= 1) {
    esum += __shfl_xor(esum, off, 64);
    a0 += __shfl_xor(a0, off, 64);
    a1 += __shfl_xor(a1, off, 64);
    a2 += __shfl_xor(a2, off, 64);
    a3 += __shfl_xor(a3, off, 64);
  }
  if (lane < 8) {
    float r = 1.f / esum;
    int c = sl * 4;
    float4 bv = *(const float4*)&b2[c];
    float vx = a0 * r + bv.x, vy = a1 * r + bv.y, vz = a2 * r + bv.z, vw = a3 * r + bv.w;
    *(float4*)&out[(size_t)n * 32 + c] =
        make_float4(1.f / (1.f + __expf(-vx)), 1.f / (1.f + __expf(-vy)),
                    1.f / (1.f + __expf(-vz)), 1.f / (1.f + __expf(-vw)));
  }
}

// ---------------- launch ----------------
extern "C" void kernel_launch(void* const* d_in, const int* in_sizes, int n_in,
                              void* d_out, int out_size, void* d_ws, size_t ws_size,
                              hipStream_t stream) {
  (void)in_sizes; (void)n_in; (void)out_size; (void)ws_size;
  const float* x      = (const float*)d_in[0];
  const void*  eb     = d_in[1];
  const float* W1     = (const float*)d_in[2];
  const float* a_src1 = (const float*)d_in[3];
  const float* a_dst1 = (const float*)d_in[4];
  const float* b1     = (const float*)d_in[5];
  const float* W2     = (const float*)d_in[6];
  const float* a_src2 = (const float*)d_in[7];
  const float* a_dst2 = (const float*)d_in[8];
  const float* b2     = (const float*)d_in[9];
  float* out = (float*)d_out;

  char* w = (char*)d_ws;
  auto alloc = [&](size_t bytes) {
    char* p = w;
    w += (bytes + 255) & ~(size_t)255;
    return p;
  };
  int*          cnt  = (int*)alloc((size_t)NN * 4);
  int*          rowp = (int*)alloc((size_t)(NN + 1) * 4);
  unsigned int* pw   = (unsigned int*)alloc((size_t)NT * 4);
  int*          csr  = (int*)alloc((size_t)NT * 4);
  int*          bsum = (int*)alloc((size_t)SCAN_BLOCKS * 4);
  uint4*        Hb1  = (uint4*)alloc((size_t)NN * 128 * 2);  // bf16 [NN][128]
  float*        AS1  = (float*)alloc((size_t)NN * 16);
  float*        AD1  = (float*)alloc((size_t)NN * 16);
  uint4*        Hb2  = (uint4*)alloc((size_t)NN * 32 * 2);   // bf16 [NN][32]
  // reuse: AS2 overlays cnt (dead after rowp); AD2 overlays pw (dead after pass2)
  float* AS2 = (float*)cnt;
  float* AD2 = (float*)pw;

  hipMemsetAsync(cnt, 0, (size_t)NN * 4, stream);
  int egrid4 = (NT / 4 + 255) / 256;
  k_pass1<<<egrid4, 256, 0, stream>>>(eb, cnt, pw);
  k_bsum<<<SCAN_BLOCKS, 256, 0, stream>>>(cnt, bsum);
  k_rowp<<<SCAN_BLOCKS, 256, 0, stream>>>(cnt, bsum, rowp);
  k_pass2<<<egrid4, 256, 0, stream>>>(eb, rowp, pw, csr);

  k_gemm1<<<(NN + 31) / 32, 256, 0, stream>>>(x, W1, a_src1, a_dst1,
                                              (unsigned int*)Hb1, AS1, AD1);
  k_l1g2<<<(NN + 3) / 4, 256, 0, stream>>>(rowp, csr, Hb1, AS1, AD1, b1, W2,
                                           a_src2, a_dst2, Hb2, AS2, AD2);
  k_l2node<<<(NN + 3) / 4, 256, 0, stream>>>(rowp, csr, (const uint2*)Hb2, AS2, AD2,
                                             b2, out);
}

// Round 15
// 272.014 us; speedup vs baseline: 1.0449x; 1.0449x over previous
//
#include <hip/hip_runtime.h>
#include <math.h>

#define NN 50000
#define NE 800000
#define NT (NN + NE)     // 850000 edges incl self-loops; NE,NT divisible by 4
#define SCAN_BLOCKS 196  // 196*256 = 50176 >= NN

__device__ __forceinline__ float lrelu(float a) { return a > 0.f ? a : 0.2f * a; }

__device__ __forceinline__ float sel4(float4 v, int h) {
  float r = v.x;
  r = (h == 1) ? v.y : r;
  r = (h == 2) ? v.z : r;
  r = (h == 3) ? v.w : r;
  return r;
}

// bf16 helpers: packed pair = lo | hi<<16, RNE rounding
__device__ __forceinline__ unsigned int f2bf(float f) {
  unsigned int u = __float_as_uint(f);
  return (u + 0x7FFFu + ((u >> 16) & 1u)) >> 16;
}
__device__ __forceinline__ unsigned int packbf(float lo, float hi) {
  return f2bf(lo) | (f2bf(hi) << 16);
}
__device__ __forceinline__ float bflo(unsigned int v) { return __uint_as_float(v << 16); }
__device__ __forceinline__ float bfhi(unsigned int v) { return __uint_as_float(v & 0xFFFF0000u); }

// per-wave int64 detection: probe odd 32-bit words of the wave's first 64 src
// entries. int64 => high words all zero. Wave edge-chunks are 256-aligned and
// NE % 256 == 0, so a wave is entirely in the edge region or entirely self-loop.
__device__ __forceinline__ int wave_is64(const void* eb, int wbase, int lane) {
  unsigned int probe = ((const unsigned int*)eb)[2 * (size_t)(wbase + lane) + 1];
  return (__ballot(probe != 0u) == 0ULL) ? 1 : 0;
}

// ---------------- CSR build pass 1: within-segment ranks (4 edges/thread) ----------
__global__ __launch_bounds__(256) void k_pass1(const void* __restrict__ eb,
                                               int* __restrict__ cnt,
                                               unsigned int* __restrict__ pw) {
  int e0 = (blockIdx.x * 256 + threadIdx.x) * 4;
  if (e0 >= NT) return;
  int lane = threadIdx.x & 63;
  int d0, d1, d2, d3;
  if (e0 < NE) {
    int wbase = (blockIdx.x * 256 + (threadIdx.x & ~63)) * 4;
    int is64 = wave_is64(eb, wbase, lane);
    if (is64) {
      const uint4* p = (const uint4*)((const unsigned int*)eb + 2 * ((size_t)NE + e0));
      uint4 a = p[0], b = p[1];
      d0 = (int)a.x; d1 = (int)a.z; d2 = (int)b.x; d3 = (int)b.z;
    } else {
      int4 v = *(const int4*)((const int*)eb + (size_t)NE + e0);
      d0 = v.x; d1 = v.y; d2 = v.z; d3 = v.w;
    }
  } else {
    d0 = e0 - NE; d1 = d0 + 1; d2 = d0 + 2; d3 = d0 + 3;
  }
  unsigned int p0 = (unsigned int)atomicAdd(&cnt[d0], 1);
  unsigned int p1 = (unsigned int)atomicAdd(&cnt[d1], 1);
  unsigned int p2 = (unsigned int)atomicAdd(&cnt[d2], 1);
  unsigned int p3 = (unsigned int)atomicAdd(&cnt[d3], 1);
  *(uint4*)&pw[e0] = make_uint4(p0, p1, p2, p3);
}

// block sums of cnt
__global__ __launch_bounds__(256) void k_bsum(const int* __restrict__ cnt,
                                              int* __restrict__ bsum) {
  int i = blockIdx.x * 256 + threadIdx.x;
  int v = (i < NN) ? cnt[i] : 0;
#pragma unroll
  for (int off = 1; off < 64; off <<= 1) v += __shfl_xor(v, off, 64);
  __shared__ int ws[4];
  int lane = threadIdx.x & 63, wid = threadIdx.x >> 6;
  if (lane == 0) ws[wid] = v;
  __syncthreads();
  if (threadIdx.x == 0) bsum[blockIdx.x] = ws[0] + ws[1] + ws[2] + ws[3];
}

// rowp: each block redundantly scans bsum (196 entries) for its base offset,
// then does the block-local exclusive scan of its cnt chunk.
__global__ __launch_bounds__(256) void k_rowp(const int* __restrict__ cnt,
                                              const int* __restrict__ bsum,
                                              int* __restrict__ rowp) {
  __shared__ int pref[256];
  __shared__ int wsum1[4], woff1[4];
  int t = threadIdx.x;
  int lane = t & 63, wid = t >> 6;
  // phase 1: exclusive scan of bsum -> pref
  {
    int v = (t < SCAN_BLOCKS) ? bsum[t] : 0;
    int incl = v;
#pragma unroll
    for (int off = 1; off < 64; off <<= 1) {
      int u = __shfl_up(incl, off, 64);
      if (lane >= off) incl += u;
    }
    if (lane == 63) wsum1[wid] = incl;
    __syncthreads();
    if (t == 0) {
      woff1[0] = 0;
      woff1[1] = wsum1[0];
      woff1[2] = wsum1[0] + wsum1[1];
      woff1[3] = wsum1[0] + wsum1[1] + wsum1[2];
    }
    __syncthreads();
    pref[t] = woff1[wid] + incl - v;
    __syncthreads();
  }
  int boffb = pref[blockIdx.x];
  // phase 2: local scan of this block's cnt chunk
  __shared__ int wsum2[4], woff2[4];
  int i = blockIdx.x * 256 + t;
  int v = (i < NN) ? cnt[i] : 0;
  int incl = v;
#pragma unroll
  for (int off = 1; off < 64; off <<= 1) {
    int u = __shfl_up(incl, off, 64);
    if (lane >= off) incl += u;
  }
  if (lane == 63) wsum2[wid] = incl;
  __syncthreads();
  if (t == 0) {
    woff2[0] = 0;
    woff2[1] = wsum2[0];
    woff2[2] = wsum2[0] + wsum2[1];
    woff2[3] = wsum2[0] + wsum2[1] + wsum2[2];
  }
  __syncthreads();
  if (i < NN) rowp[i] = boffb + woff2[wid] + incl - v;
  if (blockIdx.x == 0 && t == 0) rowp[NN] = NT;
}

// ---------------- CSR build pass 2: deterministic scatter, no atomics ---------------
__global__ __launch_bounds__(256) void k_pass2(const void* __restrict__ eb,
                                               const int* __restrict__ rowp,
                                               const unsigned int* __restrict__ pw,
                                               int* __restrict__ csr) {
  int e0 = (blockIdx.x * 256 + threadIdx.x) * 4;
  if (e0 >= NT) return;
  int lane = threadIdx.x & 63;
  int s0, s1, s2, s3, d0, d1, d2, d3;
  if (e0 < NE) {
    int wbase = (blockIdx.x * 256 + (threadIdx.x & ~63)) * 4;
    int is64 = wave_is64(eb, wbase, lane);
    if (is64) {
      const uint4* ps = (const uint4*)((const unsigned int*)eb + 2 * (size_t)e0);
      uint4 a = ps[0], b = ps[1];
      s0 = (int)a.x; s1 = (int)a.z; s2 = (int)b.x; s3 = (int)b.z;
      const uint4* pd = (const uint4*)((const unsigned int*)eb + 2 * ((size_t)NE + e0));
      uint4 c = pd[0], d = pd[1];
      d0 = (int)c.x; d1 = (int)c.z; d2 = (int)d.x; d3 = (int)d.z;
    } else {
      int4 vs = *(const int4*)((const int*)eb + (size_t)e0);
      s0 = vs.x; s1 = vs.y; s2 = vs.z; s3 = vs.w;
      int4 vd = *(const int4*)((const int*)eb + (size_t)NE + e0);
      d0 = vd.x; d1 = vd.y; d2 = vd.z; d3 = vd.w;
    }
  } else {
    s0 = d0 = e0 - NE;
    s1 = d1 = d0 + 1;
    s2 = d2 = d0 + 2;
    s3 = d3 = d0 + 3;
  }
  uint4 pv = *(const uint4*)&pw[e0];
  csr[rowp[d0] + (int)pv.x] = s0;
  csr[rowp[d1] + (int)pv.y] = s1;
  csr[rowp[d2] + (int)pv.z] = s2;
  csr[rowp[d3] + (int)pv.w] = s3;
}

// ---------------- GEMM1 + fused attn1: 32x128 tile, 8x2 blocking --------------------
__global__ __launch_bounds__(256) void k_gemm1(const float* __restrict__ X,
                                               const float* __restrict__ W,
                                               const float* __restrict__ a_src,
                                               const float* __restrict__ a_dst,
                                               unsigned int* __restrict__ Hb,
                                               float* __restrict__ AS,
                                               float* __restrict__ AD) {
  __shared__ float xt[32 * 36];   // xt[k][row]
  __shared__ float wt[32 * 132];  // wt[k][col]
  int tid = threadIdx.x;
  int tr = tid >> 6, tc = tid & 63;
  int r0 = blockIdx.x * 32;
  float acc[8][2];
#pragma unroll
  for (int i = 0; i < 8; ++i) {
    acc[i][0] = 0.f;
    acc[i][1] = 0.f;
  }

  for (int kb = 0; kb < 4; ++kb) {
    __syncthreads();
    {
      int row = tid >> 3, k4 = tid & 7;
      int gr = r0 + row;
      float4 v = make_float4(0.f, 0.f, 0.f, 0.f);
      if (gr < NN) v = ((const float4*)X)[(size_t)gr * 32 + kb * 8 + k4];
      xt[(k4 * 4 + 0) * 36 + row] = v.x;
      xt[(k4 * 4 + 1) * 36 + row] = v.y;
      xt[(k4 * 4 + 2) * 36 + row] = v.z;
      xt[(k4 * 4 + 3) * 36 + row] = v.w;
    }
#pragma unroll
    for (int i = tid; i < 1024; i += 256) {
      int kr = i >> 5, c4 = i & 31;
      *(float4*)&wt[kr * 132 + c4 * 4] = ((const float4*)W)[(size_t)(kb * 32 + kr) * 32 + c4];
    }
    __syncthreads();
#pragma unroll 4
    for (int k = 0; k < 32; ++k) {
      float4 xa = *(const float4*)&xt[k * 36 + tr * 8];
      float4 xb = *(const float4*)&xt[k * 36 + tr * 8 + 4];
      float2 wv = *(const float2*)&wt[k * 132 + tc * 2];
      float xr[8] = {xa.x, xa.y, xa.z, xa.w, xb.x, xb.y, xb.z, xb.w};
#pragma unroll
      for (int i = 0; i < 8; ++i) {
        acc[i][0] += xr[i] * wv.x;
        acc[i][1] += xr[i] * wv.y;
      }
    }
  }
  int head = tc >> 4;
  float2 sv = *(const float2*)&a_src[tc * 2];
  float2 dv = *(const float2*)&a_dst[tc * 2];
#pragma unroll
  for (int i = 0; i < 8; ++i) {
    int gr = r0 + tr * 8 + i;
    float ps = acc[i][0] * sv.x + acc[i][1] * sv.y;
    float pd = acc[i][0] * dv.x + acc[i][1] * dv.y;
#pragma unroll
    for (int off = 1; off < 16; off <<= 1) {
      ps += __shfl_xor(ps, off, 64);
      pd += __shfl_xor(pd, off, 64);
    }
    if (gr < NN) {
      Hb[(size_t)gr * 64 + tc] = packbf(acc[i][0], acc[i][1]);
      if ((tc & 15) == 0) {
        AS[gr * 4 + head] = ps;
        AD[gr * 4 + head] = pd;
      }
    }
  }
}

// ---------------- layer-1: single-pass fused softmax + aggregation (wave per dst) ----
// HMb (bf16 [NN][128]) = softmax-weighted sum + bias + relu
__global__ __launch_bounds__(256) void k_l1node(const int* __restrict__ rowp,
                                                const int* __restrict__ csr,
                                                const uint4* __restrict__ Hb,
                                                const float* __restrict__ AS,
                                                const float* __restrict__ AD,
                                                const float* __restrict__ b1,
                                                uint4* __restrict__ HMb) {
  int lane = threadIdx.x & 63, wid = threadIdx.x >> 6;
  int n = blockIdx.x * 4 + wid;
  if (n >= NN) return;
  int beg = rowp[n], end = rowp[n + 1];
  float4 ad4 = *(const float4*)&AD[n * 4];

  int sl = lane & 15;   // row slot: 8 cols at sl*8 (bf16 row = 16 uint4)
  int g = lane >> 4;    // subgroup 0..3, one edge each
  int hd = sl >> 2;     // head of these 8 cols
  float adh = sel4(ad4, hd);

  float a0 = 0.f, a1 = 0.f, a2 = 0.f, a3 = 0.f, a4 = 0.f, a5 = 0.f, a6 = 0.f, a7 = 0.f;
  float esum = 0.f;
  int i = beg + g;
  for (; i + 4 < end; i += 8) {
    int sA = csr[i];
    int sB = csr[i + 4];
    float lA = AS[sA * 4 + hd];
    float lB = AS[sB * 4 + hd];
    uint4 hA = Hb[(size_t)sA * 16 + sl];
    uint4 hB = Hb[(size_t)sB * 16 + sl];
    float wA = __expf(lrelu(lA + adh));
    float wB = __expf(lrelu(lB + adh));
    esum += wA + wB;
    a0 += wA * bflo(hA.x) + wB * bflo(hB.x);
    a1 += wA * bfhi(hA.x) + wB * bfhi(hB.x);
    a2 += wA * bflo(hA.y) + wB * bflo(hB.y);
    a3 += wA * bfhi(hA.y) + wB * bfhi(hB.y);
    a4 += wA * bflo(hA.z) + wB * bflo(hB.z);
    a5 += wA * bfhi(hA.z) + wB * bfhi(hB.z);
    a6 += wA * bflo(hA.w) + wB * bflo(hB.w);
    a7 += wA * bfhi(hA.w) + wB * bfhi(hB.w);
  }
  if (i < end) {
    int s = csr[i];
    float l = AS[s * 4 + hd];
    uint4 hv = Hb[(size_t)s * 16 + sl];
    float w0 = __expf(lrelu(l + adh));
    esum += w0;
    a0 += w0 * bflo(hv.x);
    a1 += w0 * bfhi(hv.x);
    a2 += w0 * bflo(hv.y);
    a3 += w0 * bfhi(hv.y);
    a4 += w0 * bflo(hv.z);
    a5 += w0 * bfhi(hv.z);
    a6 += w0 * bflo(hv.w);
    a7 += w0 * bfhi(hv.w);
  }
#pragma unroll
  for (int off = 16; off < 64; off <<= 1) {
    esum += __shfl_xor(esum, off, 64);
    a0 += __shfl_xor(a0, off, 64);
    a1 += __shfl_xor(a1, off, 64);
    a2 += __shfl_xor(a2, off, 64);
    a3 += __shfl_xor(a3, off, 64);
    a4 += __shfl_xor(a4, off, 64);
    a5 += __shfl_xor(a5, off, 64);
    a6 += __shfl_xor(a6, off, 64);
    a7 += __shfl_xor(a7, off, 64);
  }
  if (lane < 16) {
    float r = 1.f / esum;
    int c = sl * 8;
    float4 bva = *(const float4*)&b1[c];
    float4 bvb = *(const float4*)&b1[c + 4];
    float v0 = fmaxf(a0 * r + bva.x, 0.f);
    float v1 = fmaxf(a1 * r + bva.y, 0.f);
    float v2 = fmaxf(a2 * r + bva.z, 0.f);
    float v3 = fmaxf(a3 * r + bva.w, 0.f);
    float v4 = fmaxf(a4 * r + bvb.x, 0.f);
    float v5 = fmaxf(a5 * r + bvb.y, 0.f);
    float v6 = fmaxf(a6 * r + bvb.z, 0.f);
    float v7 = fmaxf(a7 * r + bvb.w, 0.f);
    HMb[(size_t)n * 16 + sl] =
        make_uint4(packbf(v0, v1), packbf(v2, v3), packbf(v4, v5), packbf(v6, v7));
  }
}

// ---------------- GEMM2 + attn2 epilogue: 4 threads/row, 64 rows/block ---------------
// Hb2 (bf16 dense 64B rows) = HMb @ W2; AS/AD 1-head dots
__global__ __launch_bounds__(256) void k_gemm2(const uint4* __restrict__ HMb,
                                               const float* __restrict__ W2,
                                               const float* __restrict__ a_src2,
                                               const float* __restrict__ a_dst2,
                                               uint4* __restrict__ Hb2,
                                               float* __restrict__ AS,
                                               float* __restrict__ AD) {
  __shared__ float wsm[128 * 32];  // 16 KB, only LDS use
  int tid = threadIdx.x;
  for (int i = tid; i < 1024; i += 256) ((float4*)wsm)[i] = ((const float4*)W2)[i];
  __syncthreads();
  int rl = tid >> 2, sub = tid & 3;  // 64 rows/block, 4 K-slices/row
  int r = blockIdx.x * 64 + rl;
  float acc[32];
#pragma unroll
  for (int j = 0; j < 32; ++j) acc[j] = 0.f;

  if (r < NN) {
    const uint4* xp = &HMb[(size_t)r * 16 + sub * 4];  // 32 bf16 K-slice
    uint4 xq0 = xp[0], xq1 = xp[1], xq2 = xp[2], xq3 = xp[3];
    int kbase = sub * 32;
    unsigned int wds[16] = {xq0.x, xq0.y, xq0.z, xq0.w, xq1.x, xq1.y, xq1.z, xq1.w,
                            xq2.x, xq2.y, xq2.z, xq2.w, xq3.x, xq3.y, xq3.z, xq3.w};
#pragma unroll
    for (int t = 0; t < 16; ++t) {
      float xlo = bflo(wds[t]);
      float xhi = bfhi(wds[t]);
      const float4* wr0 = (const float4*)&wsm[(kbase + t * 2) * 32];
      const float4* wr1 = (const float4*)&wsm[(kbase + t * 2 + 1) * 32];
#pragma unroll
      for (int j4 = 0; j4 < 8; ++j4) {
        float4 w0 = wr0[j4];
        float4 w1 = wr1[j4];
        acc[j4 * 4 + 0] += xlo * w0.x + xhi * w1.x;
        acc[j4 * 4 + 1] += xlo * w0.y + xhi * w1.y;
        acc[j4 * 4 + 2] += xlo * w0.z + xhi * w1.z;
        acc[j4 * 4 + 3] += xlo * w0.w + xhi * w1.w;
      }
    }
  }
  // reduce the 4 K-slices
#pragma unroll
  for (int j = 0; j < 32; ++j) {
    acc[j] += __shfl_xor(acc[j], 1, 64);
    acc[j] += __shfl_xor(acc[j], 2, 64);
  }
  if (r < NN) {
    int c = sub * 8;  // this lane writes cols c..c+7
    float4 sv0 = ((const float4*)a_src2)[sub * 2];
    float4 sv1 = ((const float4*)a_src2)[sub * 2 + 1];
    float4 dv0 = ((const float4*)a_dst2)[sub * 2];
    float4 dv1 = ((const float4*)a_dst2)[sub * 2 + 1];
    float ps = acc[c + 0] * sv0.x + acc[c + 1] * sv0.y + acc[c + 2] * sv0.z +
               acc[c + 3] * sv0.w + acc[c + 4] * sv1.x + acc[c + 5] * sv1.y +
               acc[c + 6] * sv1.z + acc[c + 7] * sv1.w;
    float pd = acc[c + 0] * dv0.x + acc[c + 1] * dv0.y + acc[c + 2] * dv0.z +
               acc[c + 3] * dv0.w + acc[c + 4] * dv1.x + acc[c + 5] * dv1.y +
               acc[c + 6] * dv1.z + acc[c + 7] * dv1.w;
    ps += __shfl_xor(ps, 1, 64);
    ps += __shfl_xor(ps, 2, 64);
    pd += __shfl_xor(pd, 1, 64);
    pd += __shfl_xor(pd, 2, 64);
    Hb2[(size_t)r * 4 + sub] =
        make_uint4(packbf(acc[c + 0], acc[c + 1]), packbf(acc[c + 2], acc[c + 3]),
                   packbf(acc[c + 4], acc[c + 5]), packbf(acc[c + 6], acc[c + 7]));
    if (sub == 0) {
      AS[r] = ps;
      AD[r] = pd;
    }
  }
}

// ---------------- layer-2: single-pass fused softmax + aggregation + sigmoid --------
__global__ __launch_bounds__(256) void k_l2node(const int* __restrict__ rowp,
                                                const int* __restrict__ csr,
                                                const uint2* __restrict__ Hb2,
                                                const float* __restrict__ AS,
                                                const float* __restrict__ AD,
                                                const float* __restrict__ b2,
                                                float* __restrict__ out) {
  int lane = threadIdx.x & 63, wid = threadIdx.x >> 6;
  int n = blockIdx.x * 4 + wid;
  if (n >= NN) return;
  int beg = rowp[n], end = rowp[n + 1];
  float adn = AD[n];

  int sl = lane & 7;  // 4 cols at sl*4 (bf16 row = 8 uint2 = 64B)
  int g = lane >> 3;  // subgroup 0..7, one edge each
  float a0 = 0.f, a1 = 0.f, a2 = 0.f, a3 = 0.f;
  float esum = 0.f;
  int i = beg + g;
  for (; i + 8 < end; i += 16) {
    int sA = csr[i];
    int sB = csr[i + 8];
    float lA = AS[sA];
    float lB = AS[sB];
    uint2 hA = Hb2[(size_t)sA * 8 + sl];
    uint2 hB = Hb2[(size_t)sB * 8 + sl];
    float wA = __expf(lrelu(lA + adn));
    float wB = __expf(lrelu(lB + adn));
    esum += wA + wB;
    a0 += wA * bflo(hA.x) + wB * bflo(hB.x);
    a1 += wA * bfhi(hA.x) + wB * bfhi(hB.x);
    a2 += wA * bflo(hA.y) + wB * bflo(hB.y);
    a3 += wA * bfhi(hA.y) + wB * bfhi(hB.y);
  }
  if (i < end) {
    int s = csr[i];
    float l = AS[s];
    uint2 hv = Hb2[(size_t)s * 8 + sl];
    float w0 = __expf(lrelu(l + adn));
    esum += w0;
    a0 += w0 * bflo(hv.x);
    a1 += w0 * bfhi(hv.x);
    a2 += w0 * bflo(hv.y);
    a3 += w0 * bfhi(hv.y);
  }
#pragma unroll
  for (int off = 8; off < 64; off <<= 1) {
    esum += __shfl_xor(esum, off, 64);
    a0 += __shfl_xor(a0, off, 64);
    a1 += __shfl_xor(a1, off, 64);
    a2 += __shfl_xor(a2, off, 64);
    a3 += __shfl_xor(a3, off, 64);
  }
  if (lane < 8) {
    float r = 1.f / esum;
    int c = sl * 4;
    float4 bv = *(const float4*)&b2[c];
    float vx = a0 * r + bv.x, vy = a1 * r + bv.y, vz = a2 * r + bv.z, vw = a3 * r + bv.w;
    *(float4*)&out[(size_t)n * 32 + c] =
        make_float4(1.f / (1.f + __expf(-vx)), 1.f / (1.f + __expf(-vy)),
                    1.f / (1.f + __expf(-vz)), 1.f / (1.f + __expf(-vw)));
  }
}

// ---------------- launch ----------------
extern "C" void kernel_launch(void* const* d_in, const int* in_sizes, int n_in,
                              void* d_out, int out_size, void* d_ws, size_t ws_size,
                              hipStream_t stream) {
  (void)in_sizes; (void)n_in; (void)out_size; (void)ws_size;
  const float* x      = (const float*)d_in[0];
  const void*  eb     = d_in[1];
  const float* W1     = (const float*)d_in[2];
  const float* a_src1 = (const float*)d_in[3];
  const float* a_dst1 = (const float*)d_in[4];
  const float* b1     = (const float*)d_in[5];
  const float* W2     = (const float*)d_in[6];
  const float* a_src2 = (const float*)d_in[7];
  const float* a_dst2 = (const float*)d_in[8];
  const float* b2     = (const float*)d_in[9];
  float* out = (float*)d_out;

  char* w = (char*)d_ws;
  auto alloc = [&](size_t bytes) {
    char* p = w;
    w += (bytes + 255) & ~(size_t)255;
    return p;
  };
  int*          cnt  = (int*)alloc((size_t)NN * 4);
  int*          rowp = (int*)alloc((size_t)(NN + 1) * 4);
  unsigned int* pw   = (unsigned int*)alloc((size_t)NT * 4);
  int*          csr  = (int*)alloc((size_t)NT * 4);
  int*          bsum = (int*)alloc((size_t)SCAN_BLOCKS * 4);
  uint4*        Hb1  = (uint4*)alloc((size_t)NN * 128 * 2);  // bf16 [NN][128]
  float*        AS1  = (float*)alloc((size_t)NN * 16);
  float*        AD1  = (float*)alloc((size_t)NN * 16);
  uint4*        HMb  = (uint4*)alloc((size_t)NN * 128 * 2);  // bf16 [NN][128]
  uint4*        Hb2  = Hb1;  // overlays Hb1 (dead after l1node)
  float*        AS2  = (float*)cnt;  // overlays cnt (dead after rowp)
  float*        AD2  = (float*)pw;   // overlays pw (dead after pass2)

  hipMemsetAsync(cnt, 0, (size_t)NN * 4, stream);
  int egrid4 = (NT / 4 + 255) / 256;
  k_pass1<<<egrid4, 256, 0, stream>>>(eb, cnt, pw);
  k_bsum<<<SCAN_BLOCKS, 256, 0, stream>>>(cnt, bsum);
  k_rowp<<<SCAN_BLOCKS, 256, 0, stream>>>(cnt, bsum, rowp);
  k_pass2<<<egrid4, 256, 0, stream>>>(eb, rowp, pw, csr);

  k_gemm1<<<(NN + 31) / 32, 256, 0, stream>>>(x, W1, a_src1, a_dst1,
                                              (unsigned int*)Hb1, AS1, AD1);
  k_l1node<<<(NN + 3) / 4, 256, 0, stream>>>(rowp, csr, Hb1, AS1, AD1, b1, HMb);
  k_gemm2<<<(NN + 63) / 64, 256, 0, stream>>>(HMb, W2, a_src2, a_dst2, Hb2, AS2, AD2);
  k_l2node<<<(NN + 3) / 4, 256, 0, stream>>>(rowp, csr, (const uint2*)Hb2, AS2, AD2,
                                             b2, out);
}